// Round 8
// baseline (385.881 us; speedup 1.0000x reference)
//
#include <hip/hip_runtime.h>
#include <math.h>

#define HW 4096   // H*W = 64*64; B=4, C=64, H=W=64, L=4096

typedef short bf16x8 __attribute__((ext_vector_type(8)));
typedef float floatx4 __attribute__((ext_vector_type(4)));

__device__ __forceinline__ unsigned short f2bf_rne(float x) {
    unsigned int u = __float_as_uint(x);
    unsigned int r = (u + 0x7FFFu + ((u >> 16) & 1u)) >> 16;
    return (unsigned short)r;
}
__device__ __forceinline__ float bf2f(unsigned short h) {
    return __uint_as_float(((unsigned int)h) << 16);
}

// ---------------- prep: split fp32 -> bf16 (hi,lo), transpose to [p][c], ------
// fused per-pixel squared norms. Aq[b][p] = [Qh|Qh|Ql], Bq[b][p] = [Kh|Kl|Kh]
// so a 192-dot gives QhKh + QhKl + QlKh ~= fp32 dot.
__global__ __launch_bounds__(256)
void prep_kernel(const float* __restrict__ Q, const float* __restrict__ K,
                 unsigned short* __restrict__ Aq, unsigned short* __restrict__ Bq,
                 float* __restrict__ pix2q, float* __restrict__ pix2k) {
    __shared__ float sT[64][65];
    const int tid = threadIdx.x;
    const int p0 = blockIdx.x * 64;
    const int b = blockIdx.y;
    const int pp = tid >> 2, qt = tid & 3;
    const size_t base = ((size_t)b * 4096 + p0 + pp) * 192;

#pragma unroll
    for (int it = 0; it < 16; ++it) {
        int idx = it * 256 + tid;
        int c = idx >> 6, x = idx & 63;
        sT[c][x] = Q[((size_t)b * 64 + c) * HW + p0 + x];
    }
    __syncthreads();
    {
        float sq = 0.f;
#pragma unroll
        for (int i = 0; i < 16; ++i) {
            int c = qt * 16 + i;
            float x = sT[c][pp];
            sq = fmaf(x, x, sq);
            unsigned short h = f2bf_rne(x);
            unsigned short l = f2bf_rne(x - bf2f(h));
            Aq[base + c] = h;
            Aq[base + 64 + c] = h;
            Aq[base + 128 + c] = l;
        }
        sq += __shfl_xor(sq, 1, 64);
        sq += __shfl_xor(sq, 2, 64);
        if (qt == 0) pix2q[(b << 12) + p0 + pp] = sq;
    }
    __syncthreads();

#pragma unroll
    for (int it = 0; it < 16; ++it) {
        int idx = it * 256 + tid;
        int c = idx >> 6, x = idx & 63;
        sT[c][x] = K[((size_t)b * 64 + c) * HW + p0 + x];
    }
    __syncthreads();
    {
        float sk = 0.f;
#pragma unroll
        for (int i = 0; i < 16; ++i) {
            int c = qt * 16 + i;
            float x = sT[c][pp];
            sk = fmaf(x, x, sk);
            unsigned short h = f2bf_rne(x);
            unsigned short l = f2bf_rne(x - bf2f(h));
            Bq[base + c] = h;
            Bq[base + 64 + c] = l;
            Bq[base + 128 + c] = h;
        }
        sk += __shfl_xor(sk, 1, 64);
        sk += __shfl_xor(sk, 2, 64);
        if (qt == 0) pix2k[(b << 12) + p0 + pp] = sk;
    }
}

// ---------------- patch reciprocal norms: 1/max(sqrt(3x3 box sum), 1e-12) ----
__global__ void patchnorm_kernel(const float* __restrict__ pix2q, const float* __restrict__ pix2k,
                                 float* __restrict__ rnq, float* __restrict__ rnk) {
    int idx = blockIdx.x * 256 + threadIdx.x;   // b*4096 + p
    int b = idx >> 12, p = idx & 4095;
    int py = p >> 6, px = p & 63;
    float sq = 0.f, sk = 0.f;
    for (int dy = -1; dy <= 1; ++dy)
        for (int dx = -1; dx <= 1; ++dx) {
            int yy = py + dy, xx = px + dx;
            if ((unsigned)yy < 64u && (unsigned)xx < 64u) {
                int o = (b << 12) + (yy << 6) + xx;
                sq += pix2q[o];
                sk += pix2k[o];
            }
        }
    rnq[idx] = 1.f / fmaxf(sqrtf(sq), 1e-12f);
    rnk[idx] = 1.f / fmaxf(sqrtf(sk), 1e-12f);
}

// ---------------- fused MFMA GEMM (K=576: y-3sum in K) + x-3sum + argmax -----
// Stage s = (dy, seg): A/B rows offset by (dy-1)*64, zero outside the image.
// Epilogue split into two 64-q-row phases (qx masks fall exactly on the 64-row
// boundary), Csh 64x133 (34 KB) -> 4 blocks/CU. Partials: 128 per q, layout
// part[(b*128 + s)][q] (s = ktile*4 + quarter) for coalesced stores.
__global__ __launch_bounds__(256, 4)
void gemm_fused_kernel(const unsigned short* __restrict__ Aq, const unsigned short* __restrict__ Bq,
                       const float* __restrict__ rnkA,
                       float* __restrict__ part_val, int* __restrict__ part_arg) {
    __shared__ __align__(16) char smem[34048];   // staging 2x16 KB | epilogue Csh[64][133]
    const int tid = threadIdx.x;
    const int lane = tid & 63, wid = tid >> 6;
    const int m15 = lane & 15, quad = lane >> 4;
    const int wm = wid & 1, wn = wid >> 1;
    const int k0 = blockIdx.x * 128;
    const int q0 = blockIdx.y * 128;
    const int b = blockIdx.z;
    const unsigned short* Aqb = Aq + (size_t)b * 4096 * 192;
    const unsigned short* Bqb = Bq + (size_t)b * 4096 * 192;

    floatx4 acc[4][4];
#pragma unroll
    for (int i = 0; i < 4; ++i)
#pragma unroll
        for (int j = 0; j < 4; ++j) acc[i][j] = (floatx4)0.f;

    for (int s = 0; s < 9; ++s) {
        const int dy = s / 3;              // 0,1,2
        const int seg = s - dy * 3;        // 0,1,2
        const int rofs = (dy - 1) * 64;    // y-shift in pixel index
        // granule g of local row r at position g^(r&7) -> frag reads 2-way aliased (free)
#pragma unroll
        for (int it = 0; it < 4; ++it) {
            int slot = it * 256 + tid;
            int row = slot >> 3, pos = slot & 7;
            int G = pos ^ (row & 7);
            int ra = q0 + row + rofs;      // qy+-1, zero outside image
            int rb = k0 + row + rofs;      // ky+-1, zero outside image
            uint4 va = make_uint4(0u, 0u, 0u, 0u), vb = make_uint4(0u, 0u, 0u, 0u);
            if ((unsigned)ra < 4096u)
                va = *(const uint4*)(Aqb + (size_t)ra * 192 + seg * 64 + G * 8);
            if ((unsigned)rb < 4096u)
                vb = *(const uint4*)(Bqb + (size_t)rb * 192 + seg * 64 + G * 8);
            *(uint4*)(smem + slot * 16) = va;
            *(uint4*)(smem + 16384 + slot * 16) = vb;
        }
        __syncthreads();
#pragma unroll
        for (int kk = 0; kk < 2; ++kk) {
            bf16x8 af[4], bfr[4];
#pragma unroll
            for (int mt = 0; mt < 4; ++mt) {
                int row = wm * 64 + mt * 16 + m15;
                int pos = (kk * 4 + quad) ^ (row & 7);
                af[mt] = *(const bf16x8*)(smem + (row * 8 + pos) * 16);
            }
#pragma unroll
            for (int nt = 0; nt < 4; ++nt) {
                int row = wn * 64 + nt * 16 + m15;
                int pos = (kk * 4 + quad) ^ (row & 7);
                bfr[nt] = *(const bf16x8*)(smem + 16384 + (row * 8 + pos) * 16);
            }
#pragma unroll
            for (int mt = 0; mt < 4; ++mt)
#pragma unroll
                for (int nt = 0; nt < 4; ++nt)
                    acc[mt][nt] = __builtin_amdgcn_mfma_f32_16x16x32_bf16(
                        af[mt], bfr[nt], acc[mt][nt], 0, 0, 0);
        }
        __syncthreads();
    }

    // ---- epilogue: two 64-row phases; x-3sum + max/argmax over the 128-k tile ----
    float* Csh = (float*)smem;               // [64][133]
    const int q_l = tid & 63;
    const int qr = tid >> 6;                 // k-quarter (0..3), one per wave
    const int c0 = qr * 32;
    const float4 zero4 = make_float4(0.f, 0.f, 0.f, 0.f);

#pragma unroll
    for (int h = 0; h < 2; ++h) {
        if (h) __syncthreads();              // phase-0 readers done before overwrite
        if (wm == h) {
#pragma unroll
            for (int mt = 0; mt < 4; ++mt)
#pragma unroll
                for (int nt = 0; nt < 4; ++nt)
#pragma unroll
                    for (int j = 0; j < 4; ++j)
                        Csh[(mt * 16 + quad * 4 + j) * 133 + wn * 64 + nt * 16 + m15] =
                            acc[mt][nt][j];
        }
        __syncthreads();

        const bool qm = q_l > 0;             // qx>0: diag- allowed
        const bool qp = q_l < 63;            // qx<63: diag+ allowed
        const float* rC = Csh + q_l * 133;
        const float* rM = Csh + (q_l - 1) * 133;
        const float* rP = Csh + (q_l + 1) * 133;
        float4 prevm = (qm && c0 > 0) ? *(const float4*)&rM[c0 - 4] : zero4;
        float4 rpj   = qp ? *(const float4*)&rP[c0] : zero4;
        float bv = -INFINITY;
        int ba = 0;
#pragma unroll
        for (int j = 0; j < 8; ++j) {
            int c = c0 + 4 * j;
            float4 cen = *(const float4*)&rC[c];
            float4 rm4 = qm ? *(const float4*)&rM[c] : zero4;
            float4 rp1 = (qp && (c + 4) < 128) ? *(const float4*)&rP[c + 4] : zero4;
            float4 o;
            o.x = cen.x + (((c & 63) != 0) ? prevm.w : 0.f) + rpj.y;
            o.y = cen.y + rm4.x + rpj.z;
            o.z = cen.z + rm4.y + rpj.w;
            o.w = cen.w + rm4.z + ((((c + 3) & 63) != 63) ? rp1.x : 0.f);
            float4 rk = *(const float4*)&rnkA[(b << 12) + k0 + c];
            // ascending k + strict > = first-occurrence argmax
            float v0 = o.x * rk.x; if (v0 > bv) { bv = v0; ba = k0 + c + 0; }
            float v1 = o.y * rk.y; if (v1 > bv) { bv = v1; ba = k0 + c + 1; }
            float v2 = o.z * rk.z; if (v2 > bv) { bv = v2; ba = k0 + c + 2; }
            float v3 = o.w * rk.w; if (v3 > bv) { bv = v3; ba = k0 + c + 3; }
            prevm = rm4;
            rpj = rp1;
        }
        int q = q0 + h * 64 + q_l;
        int sidx = blockIdx.x * 4 + qr;      // ascending-k slot order
        part_val[(((b << 7) + sidx) << 12) + q] = bv;
        part_arg[(((b << 7) + sidx) << 12) + q] = ba;
    }
}

// ---------------- gather + fold, fused combine (128 k-slot partials) ---------
// Combines partials for arg rows y-1..y+1, writes S for row y, then
// T[c,y,x] = (1/9) sum_{dy,dx} Vzp[c, a(q)+d], q=(y-dy,x-dx)
__global__ __launch_bounds__(256)
void gatherS_kernel(const float* __restrict__ V,
                    const float* __restrict__ part_val, const int* __restrict__ part_arg,
                    const float* __restrict__ rnqA,
                    float* __restrict__ S_out, float* __restrict__ T_out) {
    __shared__ int sArg[192];
    const int y = blockIdx.x, b = blockIdx.y;
    const int tid = threadIdx.x;
    if (tid < 192) {
        int r = tid >> 6, x = tid & 63;
        int yy = y - 1 + r;
        int a = 0;
        if ((unsigned)yy < 64u) {
            int base = (b << 19) + (yy << 6) + x;   // part[(b*128+s)][q]
            float bv = -INFINITY; int ba = 0;
#pragma unroll 8
            for (int s = 0; s < 128; ++s) {   // ascending s = ascending k: first max wins
                float v = part_val[base + (s << 12)];
                int aa = part_arg[base + (s << 12)];
                if (v > bv) { bv = v; ba = aa; }
            }
            a = ba;
            if (r == 1) {
                int idx = (b << 12) + (yy << 6) + x;
                S_out[idx] = bv * rnqA[idx];
            }
        }
        sArg[tid] = a;
    }
    __syncthreads();

    const int x = tid & 63, cq = tid >> 6;
    int off[9];
#pragma unroll
    for (int t = 0; t < 9; ++t) {
        int dy = t / 3 - 1, dx = t % 3 - 1;
        int qy = y - dy, qx = x - dx;
        int o = -1;
        if ((unsigned)qy < 64u && (unsigned)qx < 64u) {
            int a = sArg[(1 - dy) * 64 + qx];
            int sy = (a >> 6) + dy, sx = (a & 63) + dx;
            if ((unsigned)sy < 64u && (unsigned)sx < 64u) o = (sy << 6) + sx;
        }
        off[t] = o;
    }
    const float* Vb = V + (size_t)b * 64 * HW;
    float* Tb = T_out + (size_t)b * 64 * HW + (y << 6) + x;
    for (int ci = 0; ci < 16; ++ci) {
        int c = cq * 16 + ci;
        const float* Vc = Vb + (size_t)c * HW;
        float acc = 0.f;
#pragma unroll
        for (int t = 0; t < 9; ++t)
            acc += (off[t] >= 0) ? Vc[off[t]] : 0.f;
        Tb[(size_t)c * HW] = acc * (1.f / 9.f);
    }
}

extern "C" void kernel_launch(void* const* d_in, const int* in_sizes, int n_in,
                              void* d_out, int out_size, void* d_ws, size_t ws_size,
                              hipStream_t stream) {
    const float* V = (const float*)d_in[0];
    const float* K = (const float*)d_in[1];
    const float* Q = (const float*)d_in[2];
    float* S_out = (float*)d_out;            // 4*4096
    float* T_out = S_out + 4 * HW;           // 4*64*4096

    char* ws = (char*)d_ws;
    float* pix2q = (float*)(ws + 0);                 // 64 KB
    float* pix2k = (float*)(ws + 65536);
    float* rnq   = (float*)(ws + 131072);
    float* rnk   = (float*)(ws + 196608);
    float* part_val = (float*)(ws + 262144);         // 4*128*4096 f = 8 MB
    int*   part_arg = (int*)(ws + 8650752);          // 8 MB
    unsigned short* Aq = (unsigned short*)(ws + 17039360);   // 4*4096*192 bf16 = 6 MiB
    unsigned short* Bq = (unsigned short*)(ws + 23330816);   // 6 MiB

    prep_kernel<<<dim3(64, 4), 256, 0, stream>>>(Q, K, Aq, Bq, pix2q, pix2k);
    patchnorm_kernel<<<64, 256, 0, stream>>>(pix2q, pix2k, rnq, rnk);
    gemm_fused_kernel<<<dim3(32, 32, 4), 256, 0, stream>>>(Aq, Bq, rnk, part_val, part_arg);
    gatherS_kernel<<<dim3(64, 4), 256, 0, stream>>>(V, part_val, part_arg, rnq, S_out, T_out);
}

// Round 9
// 299.145 us; speedup vs baseline: 1.2899x; 1.2899x over previous
//
#include <hip/hip_runtime.h>
#include <math.h>

#define HW 4096   // H*W = 64*64; B=4, C=64, H=W=64, L=4096

typedef short bf16x8 __attribute__((ext_vector_type(8)));
typedef float floatx4 __attribute__((ext_vector_type(4)));

__device__ __forceinline__ unsigned short f2bf_rne(float x) {
    unsigned int u = __float_as_uint(x);
    unsigned int r = (u + 0x7FFFu + ((u >> 16) & 1u)) >> 16;
    return (unsigned short)r;
}
__device__ __forceinline__ float bf2f(unsigned short h) {
    return __uint_as_float(((unsigned int)h) << 16);
}

// ---------------- prep: split fp32 -> bf16 (hi,lo), transpose to [p][c], ------
// fused per-pixel squared norms. Aq[b][p] = [Qh|Qh|Ql], Bq[b][p] = [Kh|Kl|Kh]
// so a 192-dot gives QhKh + QhKl + QlKh ~= fp32 dot.
__global__ __launch_bounds__(256)
void prep_kernel(const float* __restrict__ Q, const float* __restrict__ K,
                 unsigned short* __restrict__ Aq, unsigned short* __restrict__ Bq,
                 float* __restrict__ pix2q, float* __restrict__ pix2k) {
    __shared__ float sT[64][65];
    const int tid = threadIdx.x;
    const int p0 = blockIdx.x * 64;
    const int b = blockIdx.y;
    const int pp = tid >> 2, qt = tid & 3;
    const size_t base = ((size_t)b * 4096 + p0 + pp) * 192;

#pragma unroll
    for (int it = 0; it < 16; ++it) {
        int idx = it * 256 + tid;
        int c = idx >> 6, x = idx & 63;
        sT[c][x] = Q[((size_t)b * 64 + c) * HW + p0 + x];
    }
    __syncthreads();
    {
        float sq = 0.f;
#pragma unroll
        for (int i = 0; i < 16; ++i) {
            int c = qt * 16 + i;
            float x = sT[c][pp];
            sq = fmaf(x, x, sq);
            unsigned short h = f2bf_rne(x);
            unsigned short l = f2bf_rne(x - bf2f(h));
            Aq[base + c] = h;
            Aq[base + 64 + c] = h;
            Aq[base + 128 + c] = l;
        }
        sq += __shfl_xor(sq, 1, 64);
        sq += __shfl_xor(sq, 2, 64);
        if (qt == 0) pix2q[(b << 12) + p0 + pp] = sq;
    }
    __syncthreads();

#pragma unroll
    for (int it = 0; it < 16; ++it) {
        int idx = it * 256 + tid;
        int c = idx >> 6, x = idx & 63;
        sT[c][x] = K[((size_t)b * 64 + c) * HW + p0 + x];
    }
    __syncthreads();
    {
        float sk = 0.f;
#pragma unroll
        for (int i = 0; i < 16; ++i) {
            int c = qt * 16 + i;
            float x = sT[c][pp];
            sk = fmaf(x, x, sk);
            unsigned short h = f2bf_rne(x);
            unsigned short l = f2bf_rne(x - bf2f(h));
            Bq[base + c] = h;
            Bq[base + 64 + c] = l;
            Bq[base + 128 + c] = h;
        }
        sk += __shfl_xor(sk, 1, 64);
        sk += __shfl_xor(sk, 2, 64);
        if (qt == 0) pix2k[(b << 12) + p0 + pp] = sk;
    }
}

// ---------------- patch reciprocal norms: 1/max(sqrt(3x3 box sum), 1e-12) ----
__global__ void patchnorm_kernel(const float* __restrict__ pix2q, const float* __restrict__ pix2k,
                                 float* __restrict__ rnq, float* __restrict__ rnk) {
    int idx = blockIdx.x * 256 + threadIdx.x;   // b*4096 + p
    int b = idx >> 12, p = idx & 4095;
    int py = p >> 6, px = p & 63;
    float sq = 0.f, sk = 0.f;
    for (int dy = -1; dy <= 1; ++dy)
        for (int dx = -1; dx <= 1; ++dx) {
            int yy = py + dy, xx = px + dx;
            if ((unsigned)yy < 64u && (unsigned)xx < 64u) {
                int o = (b << 12) + (yy << 6) + xx;
                sq += pix2q[o];
                sk += pix2k[o];
            }
        }
    rnq[idx] = 1.f / fmaxf(sqrtf(sq), 1e-12f);
    rnk[idx] = 1.f / fmaxf(sqrtf(sk), 1e-12f);
}

// ---------------- fused MFMA GEMM (K=576: y-3sum in K) + x-3sum + argmax -----
// Stage s = (dy, seg): A/B rows offset by (dy-1)*64, zero outside the image.
// Two-phase 64-row epilogue, Csh 64x133 (34 KB LDS).
// __launch_bounds__(256,3): 3 blocks/CU -> 170 total regs/wave = 64 AGPR acc
// + ~106 arch VGPR. (256,4) forced 64 arch VGPRs -> scratch spills (R8).
__global__ __launch_bounds__(256, 3)
void gemm_fused_kernel(const unsigned short* __restrict__ Aq, const unsigned short* __restrict__ Bq,
                       const float* __restrict__ rnkA,
                       float* __restrict__ part_val, int* __restrict__ part_arg) {
    __shared__ __align__(16) char smem[34048];   // staging 2x16 KB | epilogue Csh[64][133]
    const int tid = threadIdx.x;
    const int lane = tid & 63, wid = tid >> 6;
    const int m15 = lane & 15, quad = lane >> 4;
    const int wm = wid & 1, wn = wid >> 1;
    const int k0 = blockIdx.x * 128;
    const int q0 = blockIdx.y * 128;
    const int b = blockIdx.z;
    const unsigned short* Aqb = Aq + (size_t)b * 4096 * 192;
    const unsigned short* Bqb = Bq + (size_t)b * 4096 * 192;

    floatx4 acc[4][4];
#pragma unroll
    for (int i = 0; i < 4; ++i)
#pragma unroll
        for (int j = 0; j < 4; ++j) acc[i][j] = (floatx4)0.f;

    for (int s = 0; s < 9; ++s) {
        const int dy = s / 3;              // 0,1,2
        const int seg = s - dy * 3;        // 0,1,2
        const int rofs = (dy - 1) * 64;    // y-shift in pixel index
        // granule g of local row r at position g^(r&7) -> frag reads 2-way aliased (free).
        // A panel first, then B panel: halves peak staging VGPR liveness.
        {
            uint4 va[4];
#pragma unroll
            for (int it = 0; it < 4; ++it) {
                int slot = it * 256 + tid;
                int row = slot >> 3, pos = slot & 7;
                int G = pos ^ (row & 7);
                int ra = q0 + row + rofs;      // qy+-1, zero outside image
                va[it] = make_uint4(0u, 0u, 0u, 0u);
                if ((unsigned)ra < 4096u)
                    va[it] = *(const uint4*)(Aqb + (size_t)ra * 192 + seg * 64 + G * 8);
            }
#pragma unroll
            for (int it = 0; it < 4; ++it)
                *(uint4*)(smem + (it * 256 + tid) * 16) = va[it];
        }
        {
            uint4 vb[4];
#pragma unroll
            for (int it = 0; it < 4; ++it) {
                int slot = it * 256 + tid;
                int row = slot >> 3, pos = slot & 7;
                int G = pos ^ (row & 7);
                int rb = k0 + row + rofs;      // ky+-1, zero outside image
                vb[it] = make_uint4(0u, 0u, 0u, 0u);
                if ((unsigned)rb < 4096u)
                    vb[it] = *(const uint4*)(Bqb + (size_t)rb * 192 + seg * 64 + G * 8);
            }
#pragma unroll
            for (int it = 0; it < 4; ++it)
                *(uint4*)(smem + 16384 + (it * 256 + tid) * 16) = vb[it];
        }
        __syncthreads();
#pragma unroll
        for (int kk = 0; kk < 2; ++kk) {
            bf16x8 af[4], bfr[4];
#pragma unroll
            for (int mt = 0; mt < 4; ++mt) {
                int row = wm * 64 + mt * 16 + m15;
                int pos = (kk * 4 + quad) ^ (row & 7);
                af[mt] = *(const bf16x8*)(smem + (row * 8 + pos) * 16);
            }
#pragma unroll
            for (int nt = 0; nt < 4; ++nt) {
                int row = wn * 64 + nt * 16 + m15;
                int pos = (kk * 4 + quad) ^ (row & 7);
                bfr[nt] = *(const bf16x8*)(smem + 16384 + (row * 8 + pos) * 16);
            }
#pragma unroll
            for (int mt = 0; mt < 4; ++mt)
#pragma unroll
                for (int nt = 0; nt < 4; ++nt)
                    acc[mt][nt] = __builtin_amdgcn_mfma_f32_16x16x32_bf16(
                        af[mt], bfr[nt], acc[mt][nt], 0, 0, 0);
        }
        __syncthreads();
    }

    // ---- epilogue: two 64-row phases; x-3sum + max/argmax over the 128-k tile ----
    float* Csh = (float*)smem;               // [64][133]
    const int q_l = tid & 63;
    const int qr = tid >> 6;                 // k-quarter (0..3), one per wave
    const int c0 = qr * 32;
    const float4 zero4 = make_float4(0.f, 0.f, 0.f, 0.f);

#pragma unroll
    for (int h = 0; h < 2; ++h) {
        if (h) __syncthreads();              // phase-0 readers done before overwrite
        if (wm == h) {
#pragma unroll
            for (int mt = 0; mt < 4; ++mt)
#pragma unroll
                for (int nt = 0; nt < 4; ++nt)
#pragma unroll
                    for (int j = 0; j < 4; ++j)
                        Csh[(mt * 16 + quad * 4 + j) * 133 + wn * 64 + nt * 16 + m15] =
                            acc[mt][nt][j];
        }
        __syncthreads();

        const bool qm = q_l > 0;             // qx>0: diag- allowed
        const bool qp = q_l < 63;            // qx<63: diag+ allowed
        const float* rC = Csh + q_l * 133;
        const float* rM = Csh + (q_l - 1) * 133;
        const float* rP = Csh + (q_l + 1) * 133;
        float4 prevm = (qm && c0 > 0) ? *(const float4*)&rM[c0 - 4] : zero4;
        float4 rpj   = qp ? *(const float4*)&rP[c0] : zero4;
        float bv = -INFINITY;
        int ba = 0;
#pragma unroll
        for (int j = 0; j < 8; ++j) {
            int c = c0 + 4 * j;
            float4 cen = *(const float4*)&rC[c];
            float4 rm4 = qm ? *(const float4*)&rM[c] : zero4;
            float4 rp1 = (qp && (c + 4) < 128) ? *(const float4*)&rP[c + 4] : zero4;
            float4 o;
            o.x = cen.x + (((c & 63) != 0) ? prevm.w : 0.f) + rpj.y;
            o.y = cen.y + rm4.x + rpj.z;
            o.z = cen.z + rm4.y + rpj.w;
            o.w = cen.w + rm4.z + ((((c + 3) & 63) != 63) ? rp1.x : 0.f);
            float4 rk = *(const float4*)&rnkA[(b << 12) + k0 + c];
            // ascending k + strict > = first-occurrence argmax
            float v0 = o.x * rk.x; if (v0 > bv) { bv = v0; ba = k0 + c + 0; }
            float v1 = o.y * rk.y; if (v1 > bv) { bv = v1; ba = k0 + c + 1; }
            float v2 = o.z * rk.z; if (v2 > bv) { bv = v2; ba = k0 + c + 2; }
            float v3 = o.w * rk.w; if (v3 > bv) { bv = v3; ba = k0 + c + 3; }
            prevm = rm4;
            rpj = rp1;
        }
        int q = q0 + h * 64 + q_l;
        int sidx = blockIdx.x * 4 + qr;      // ascending-k slot order
        part_val[(((b << 7) + sidx) << 12) + q] = bv;
        part_arg[(((b << 7) + sidx) << 12) + q] = ba;
    }
}

// ---------------- gather + fold, fused combine (128 k-slot partials) ---------
// Combines partials for arg rows y-1..y+1, writes S for row y, then
// T[c,y,x] = (1/9) sum_{dy,dx} Vzp[c, a(q)+d], q=(y-dy,x-dx)
__global__ __launch_bounds__(256)
void gatherS_kernel(const float* __restrict__ V,
                    const float* __restrict__ part_val, const int* __restrict__ part_arg,
                    const float* __restrict__ rnqA,
                    float* __restrict__ S_out, float* __restrict__ T_out) {
    __shared__ int sArg[192];
    const int y = blockIdx.x, b = blockIdx.y;
    const int tid = threadIdx.x;
    if (tid < 192) {
        int r = tid >> 6, x = tid & 63;
        int yy = y - 1 + r;
        int a = 0;
        if ((unsigned)yy < 64u) {
            int base = (b << 19) + (yy << 6) + x;   // part[(b*128+s)][q]
            float bv = -INFINITY; int ba = 0;
#pragma unroll 8
            for (int s = 0; s < 128; ++s) {   // ascending s = ascending k: first max wins
                float v = part_val[base + (s << 12)];
                int aa = part_arg[base + (s << 12)];
                if (v > bv) { bv = v; ba = aa; }
            }
            a = ba;
            if (r == 1) {
                int idx = (b << 12) + (yy << 6) + x;
                S_out[idx] = bv * rnqA[idx];
            }
        }
        sArg[tid] = a;
    }
    __syncthreads();

    const int x = tid & 63, cq = tid >> 6;
    int off[9];
#pragma unroll
    for (int t = 0; t < 9; ++t) {
        int dy = t / 3 - 1, dx = t % 3 - 1;
        int qy = y - dy, qx = x - dx;
        int o = -1;
        if ((unsigned)qy < 64u && (unsigned)qx < 64u) {
            int a = sArg[(1 - dy) * 64 + qx];
            int sy = (a >> 6) + dy, sx = (a & 63) + dx;
            if ((unsigned)sy < 64u && (unsigned)sx < 64u) o = (sy << 6) + sx;
        }
        off[t] = o;
    }
    const float* Vb = V + (size_t)b * 64 * HW;
    float* Tb = T_out + (size_t)b * 64 * HW + (y << 6) + x;
    for (int ci = 0; ci < 16; ++ci) {
        int c = cq * 16 + ci;
        const float* Vc = Vb + (size_t)c * HW;
        float acc = 0.f;
#pragma unroll
        for (int t = 0; t < 9; ++t)
            acc += (off[t] >= 0) ? Vc[off[t]] : 0.f;
        Tb[(size_t)c * HW] = acc * (1.f / 9.f);
    }
}

extern "C" void kernel_launch(void* const* d_in, const int* in_sizes, int n_in,
                              void* d_out, int out_size, void* d_ws, size_t ws_size,
                              hipStream_t stream) {
    const float* V = (const float*)d_in[0];
    const float* K = (const float*)d_in[1];
    const float* Q = (const float*)d_in[2];
    float* S_out = (float*)d_out;            // 4*4096
    float* T_out = S_out + 4 * HW;           // 4*64*4096

    char* ws = (char*)d_ws;
    float* pix2q = (float*)(ws + 0);                 // 64 KB
    float* pix2k = (float*)(ws + 65536);
    float* rnq   = (float*)(ws + 131072);
    float* rnk   = (float*)(ws + 196608);
    float* part_val = (float*)(ws + 262144);         // 4*128*4096 f = 8 MB
    int*   part_arg = (int*)(ws + 8650752);          // 8 MB
    unsigned short* Aq = (unsigned short*)(ws + 17039360);   // 4*4096*192 bf16 = 6 MiB
    unsigned short* Bq = (unsigned short*)(ws + 23330816);   // 6 MiB

    prep_kernel<<<dim3(64, 4), 256, 0, stream>>>(Q, K, Aq, Bq, pix2q, pix2k);
    patchnorm_kernel<<<64, 256, 0, stream>>>(pix2q, pix2k, rnq, rnk);
    gemm_fused_kernel<<<dim3(32, 32, 4), 256, 0, stream>>>(Aq, Bq, rnk, part_val, part_arg);
    gatherS_kernel<<<dim3(64, 4), 256, 0, stream>>>(V, part_val, part_arg, rnq, S_out, T_out);
}

// Round 10
// 250.683 us; speedup vs baseline: 1.5393x; 1.1933x over previous
//
#include <hip/hip_runtime.h>
#include <math.h>

#define HW 4096   // H*W = 64*64; B=4, C=64, H=W=64, L=4096

typedef short bf16x8 __attribute__((ext_vector_type(8)));
typedef float floatx4 __attribute__((ext_vector_type(4)));

__device__ __forceinline__ unsigned short f2bf_rne(float x) {
    unsigned int u = __float_as_uint(x);
    unsigned int r = (u + 0x7FFFu + ((u >> 16) & 1u)) >> 16;
    return (unsigned short)r;
}
__device__ __forceinline__ float bf2f(unsigned short h) {
    return __uint_as_float(((unsigned int)h) << 16);
}

// async global->LDS, 16 B per lane; LDS dest is wave-uniform base + lane*16,
// which matches our slot = it*256 + tid enumeration. CK-style addrspace casts.
__device__ __forceinline__ void gload_lds16(const void* gptr, void* lptr) {
    auto g = (const __attribute__((address_space(1))) unsigned int*)(unsigned long long)(gptr);
    auto l = (__attribute__((address_space(3))) unsigned int*)(unsigned int)(unsigned long long)(lptr);
    __builtin_amdgcn_global_load_lds(g, l, 16, 0, 0);
}

// ---------------- prep: split fp32 -> bf16 (hi,lo), transpose to [p][c], ------
// fused per-pixel squared norms. Aq[b][p] = [Qh|Qh|Ql], Bq[b][p] = [Kh|Kl|Kh]
// so a 192-dot gives QhKh + QhKl + QlKh ~= fp32 dot.
__global__ __launch_bounds__(256)
void prep_kernel(const float* __restrict__ Q, const float* __restrict__ K,
                 unsigned short* __restrict__ Aq, unsigned short* __restrict__ Bq,
                 float* __restrict__ pix2q, float* __restrict__ pix2k) {
    __shared__ float sT[64][65];
    const int tid = threadIdx.x;
    const int p0 = blockIdx.x * 64;
    const int b = blockIdx.y;
    const int pp = tid >> 2, qt = tid & 3;
    const size_t base = ((size_t)b * 4096 + p0 + pp) * 192;

#pragma unroll
    for (int it = 0; it < 16; ++it) {
        int idx = it * 256 + tid;
        int c = idx >> 6, x = idx & 63;
        sT[c][x] = Q[((size_t)b * 64 + c) * HW + p0 + x];
    }
    __syncthreads();
    {
        float sq = 0.f;
#pragma unroll
        for (int i = 0; i < 16; ++i) {
            int c = qt * 16 + i;
            float x = sT[c][pp];
            sq = fmaf(x, x, sq);
            unsigned short h = f2bf_rne(x);
            unsigned short l = f2bf_rne(x - bf2f(h));
            Aq[base + c] = h;
            Aq[base + 64 + c] = h;
            Aq[base + 128 + c] = l;
        }
        sq += __shfl_xor(sq, 1, 64);
        sq += __shfl_xor(sq, 2, 64);
        if (qt == 0) pix2q[(b << 12) + p0 + pp] = sq;
    }
    __syncthreads();

#pragma unroll
    for (int it = 0; it < 16; ++it) {
        int idx = it * 256 + tid;
        int c = idx >> 6, x = idx & 63;
        sT[c][x] = K[((size_t)b * 64 + c) * HW + p0 + x];
    }
    __syncthreads();
    {
        float sk = 0.f;
#pragma unroll
        for (int i = 0; i < 16; ++i) {
            int c = qt * 16 + i;
            float x = sT[c][pp];
            sk = fmaf(x, x, sk);
            unsigned short h = f2bf_rne(x);
            unsigned short l = f2bf_rne(x - bf2f(h));
            Bq[base + c] = h;
            Bq[base + 64 + c] = l;
            Bq[base + 128 + c] = h;
        }
        sk += __shfl_xor(sk, 1, 64);
        sk += __shfl_xor(sk, 2, 64);
        if (qt == 0) pix2k[(b << 12) + p0 + pp] = sk;
    }
}

// ---------------- patch reciprocal norms: 1/max(sqrt(3x3 box sum), 1e-12) ----
__global__ void patchnorm_kernel(const float* __restrict__ pix2q, const float* __restrict__ pix2k,
                                 float* __restrict__ rnq, float* __restrict__ rnk) {
    int idx = blockIdx.x * 256 + threadIdx.x;   // b*4096 + p
    int b = idx >> 12, p = idx & 4095;
    int py = p >> 6, px = p & 63;
    float sq = 0.f, sk = 0.f;
    for (int dy = -1; dy <= 1; ++dy)
        for (int dx = -1; dx <= 1; ++dx) {
            int yy = py + dy, xx = px + dx;
            if ((unsigned)yy < 64u && (unsigned)xx < 64u) {
                int o = (b << 12) + (yy << 6) + xx;
                sq += pix2q[o];
                sk += pix2k[o];
            }
        }
    rnq[idx] = 1.f / fmaxf(sqrtf(sq), 1e-12f);
    rnk[idx] = 1.f / fmaxf(sqrtf(sk), 1e-12f);
}

// ---------------- fused MFMA GEMM (K=576: y-3sum in K) + x-3sum + argmax -----
// seg-outer / dy-inner: per seg, stage 256-row A/B slabs (q0-64..q0+192 /
// k0-64..k0+192, seg-th 64-col slice) ONCE; the 3 dy variants are LDS row
// windows (+0/+64/+128). 6 main barriers instead of 18; 96 MFMAs per barrier
// pair. Interior tiles stage via global_load_lds (async, width 16).
// 2 blocks/CU (256,2): honest occupancy, no spills (R8/R9 lesson).
__global__ __launch_bounds__(256, 2)
void gemm_fused_kernel(const unsigned short* __restrict__ Aq, const unsigned short* __restrict__ Bq,
                       const float* __restrict__ rnkA,
                       float* __restrict__ part_val, int* __restrict__ part_arg) {
    __shared__ __align__(16) char smem[65536];   // A slab 32K | B slab 32K; epilogue Csh[64][133]
    const int tid = threadIdx.x;
    const int lane = tid & 63, wid = tid >> 6;
    const int m15 = lane & 15, quad = lane >> 4;
    const int wm = wid & 1, wn = wid >> 1;
    const int k0 = blockIdx.x * 128;
    const int q0 = blockIdx.y * 128;
    const int b = blockIdx.z;
    const char* Aqb = (const char*)(Aq + (size_t)b * 4096 * 192);
    const char* Bqb = (const char*)(Bq + (size_t)b * 4096 * 192);
    const bool aInt = (q0 >= 64) && (q0 <= 4096 - 192);   // A slab fully in-image
    const bool bInt = (k0 >= 64) && (k0 <= 4096 - 192);

    floatx4 acc[4][4];
#pragma unroll
    for (int i = 0; i < 4; ++i)
#pragma unroll
        for (int j = 0; j < 4; ++j) acc[i][j] = (floatx4)0.f;

    for (int seg = 0; seg < 3; ++seg) {
        // ---- stage A slab: rows q0-64 .. q0+192, 64-col slice seg ----
        // slot = row*8 + pos, pos = G ^ (row&7): frag b128 reads are 2-way (free)
        const char* ab = Aqb + (size_t)(q0 - 64) * 384 + seg * 128;
        const char* bb = Bqb + (size_t)(k0 - 64) * 384 + seg * 128;
        if (aInt) {
#pragma unroll
            for (int it = 0; it < 8; ++it) {
                int slot = it * 256 + tid;
                int row = slot >> 3, pos = slot & 7;
                int G = pos ^ (row & 7);
                gload_lds16(ab + (size_t)row * 384 + G * 16, smem + slot * 16);
            }
        } else {
#pragma unroll
            for (int it = 0; it < 8; ++it) {
                int slot = it * 256 + tid;
                int row = slot >> 3, pos = slot & 7;
                int G = pos ^ (row & 7);
                uint4 v = make_uint4(0u, 0u, 0u, 0u);
                if ((unsigned)(q0 - 64 + row) < 4096u)
                    v = *(const uint4*)(ab + (size_t)row * 384 + G * 16);
                *(uint4*)(smem + slot * 16) = v;
            }
        }
        if (bInt) {
#pragma unroll
            for (int it = 0; it < 8; ++it) {
                int slot = it * 256 + tid;
                int row = slot >> 3, pos = slot & 7;
                int G = pos ^ (row & 7);
                gload_lds16(bb + (size_t)row * 384 + G * 16, smem + 32768 + slot * 16);
            }
        } else {
#pragma unroll
            for (int it = 0; it < 8; ++it) {
                int slot = it * 256 + tid;
                int row = slot >> 3, pos = slot & 7;
                int G = pos ^ (row & 7);
                uint4 v = make_uint4(0u, 0u, 0u, 0u);
                if ((unsigned)(k0 - 64 + row) < 4096u)
                    v = *(const uint4*)(bb + (size_t)row * 384 + G * 16);
                *(uint4*)(smem + 32768 + slot * 16) = v;
            }
        }
        __syncthreads();   // drains vmcnt incl. global_load_lds

        // ---- 3 dy windows x 2 kk x 16 MFMA, no barriers inside ----
#pragma unroll
        for (int dy = 0; dy < 3; ++dy) {
#pragma unroll
            for (int kk = 0; kk < 2; ++kk) {
                bf16x8 af[4], bfr[4];
#pragma unroll
                for (int mt = 0; mt < 4; ++mt) {
                    int row = dy * 64 + wm * 64 + mt * 16 + m15;
                    int pos = (kk * 4 + quad) ^ (row & 7);
                    af[mt] = *(const bf16x8*)(smem + (row * 8 + pos) * 16);
                }
#pragma unroll
                for (int nt = 0; nt < 4; ++nt) {
                    int row = dy * 64 + wn * 64 + nt * 16 + m15;
                    int pos = (kk * 4 + quad) ^ (row & 7);
                    bfr[nt] = *(const bf16x8*)(smem + 32768 + (row * 8 + pos) * 16);
                }
#pragma unroll
                for (int mt = 0; mt < 4; ++mt)
#pragma unroll
                    for (int nt = 0; nt < 4; ++nt)
                        acc[mt][nt] = __builtin_amdgcn_mfma_f32_16x16x32_bf16(
                            af[mt], bfr[nt], acc[mt][nt], 0, 0, 0);
            }
        }
        __syncthreads();   // slab dead before next seg overwrites
    }

    // ---- epilogue: two 64-row phases; x-3sum + max/argmax over the 128-k tile ----
    float* Csh = (float*)smem;               // [64][133]
    const int q_l = tid & 63;
    const int qr = tid >> 6;                 // k-quarter (0..3), one per wave
    const int c0 = qr * 32;
    const float4 zero4 = make_float4(0.f, 0.f, 0.f, 0.f);

#pragma unroll
    for (int h = 0; h < 2; ++h) {
        if (h) __syncthreads();              // phase-0 readers done before overwrite
        if (wm == h) {
#pragma unroll
            for (int mt = 0; mt < 4; ++mt)
#pragma unroll
                for (int nt = 0; nt < 4; ++nt)
#pragma unroll
                    for (int j = 0; j < 4; ++j)
                        Csh[(mt * 16 + quad * 4 + j) * 133 + wn * 64 + nt * 16 + m15] =
                            acc[mt][nt][j];
        }
        __syncthreads();

        const bool qm = q_l > 0;             // qx>0: diag- allowed
        const bool qp = q_l < 63;            // qx<63: diag+ allowed
        const float* rC = Csh + q_l * 133;
        const float* rM = Csh + (q_l - 1) * 133;
        const float* rP = Csh + (q_l + 1) * 133;
        float4 prevm = (qm && c0 > 0) ? *(const float4*)&rM[c0 - 4] : zero4;
        float4 rpj   = qp ? *(const float4*)&rP[c0] : zero4;
        float bv = -INFINITY;
        int ba = 0;
#pragma unroll
        for (int j = 0; j < 8; ++j) {
            int c = c0 + 4 * j;
            float4 cen = *(const float4*)&rC[c];
            float4 rm4 = qm ? *(const float4*)&rM[c] : zero4;
            float4 rp1 = (qp && (c + 4) < 128) ? *(const float4*)&rP[c + 4] : zero4;
            float4 o;
            o.x = cen.x + (((c & 63) != 0) ? prevm.w : 0.f) + rpj.y;
            o.y = cen.y + rm4.x + rpj.z;
            o.z = cen.z + rm4.y + rpj.w;
            o.w = cen.w + rm4.z + ((((c + 3) & 63) != 63) ? rp1.x : 0.f);
            float4 rk = *(const float4*)&rnkA[(b << 12) + k0 + c];
            // ascending k + strict > = first-occurrence argmax
            float v0 = o.x * rk.x; if (v0 > bv) { bv = v0; ba = k0 + c + 0; }
            float v1 = o.y * rk.y; if (v1 > bv) { bv = v1; ba = k0 + c + 1; }
            float v2 = o.z * rk.z; if (v2 > bv) { bv = v2; ba = k0 + c + 2; }
            float v3 = o.w * rk.w; if (v3 > bv) { bv = v3; ba = k0 + c + 3; }
            prevm = rm4;
            rpj = rp1;
        }
        int q = q0 + h * 64 + q_l;
        int sidx = blockIdx.x * 4 + qr;      // ascending-k slot order
        part_val[(((b << 7) + sidx) << 12) + q] = bv;
        part_arg[(((b << 7) + sidx) << 12) + q] = ba;
    }
}

// ---------------- gather + fold, fused combine (128 k-slot partials) ---------
// Combines partials for arg rows y-1..y+1, writes S for row y, then
// T[c,y,x] = (1/9) sum_{dy,dx} Vzp[c, a(q)+d], q=(y-dy,x-dx)
__global__ __launch_bounds__(256)
void gatherS_kernel(const float* __restrict__ V,
                    const float* __restrict__ part_val, const int* __restrict__ part_arg,
                    const float* __restrict__ rnqA,
                    float* __restrict__ S_out, float* __restrict__ T_out) {
    __shared__ int sArg[192];
    const int y = blockIdx.x, b = blockIdx.y;
    const int tid = threadIdx.x;
    if (tid < 192) {
        int r = tid >> 6, x = tid & 63;
        int yy = y - 1 + r;
        int a = 0;
        if ((unsigned)yy < 64u) {
            int base = (b << 19) + (yy << 6) + x;   // part[(b*128+s)][q]
            float bv = -INFINITY; int ba = 0;
#pragma unroll 8
            for (int s = 0; s < 128; ++s) {   // ascending s = ascending k: first max wins
                float v = part_val[base + (s << 12)];
                int aa = part_arg[base + (s << 12)];
                if (v > bv) { bv = v; ba = aa; }
            }
            a = ba;
            if (r == 1) {
                int idx = (b << 12) + (yy << 6) + x;
                S_out[idx] = bv * rnqA[idx];
            }
        }
        sArg[tid] = a;
    }
    __syncthreads();

    const int x = tid & 63, cq = tid >> 6;
    int off[9];
#pragma unroll
    for (int t = 0; t < 9; ++t) {
        int dy = t / 3 - 1, dx = t % 3 - 1;
        int qy = y - dy, qx = x - dx;
        int o = -1;
        if ((unsigned)qy < 64u && (unsigned)qx < 64u) {
            int a = sArg[(1 - dy) * 64 + qx];
            int sy = (a >> 6) + dy, sx = (a & 63) + dx;
            if ((unsigned)sy < 64u && (unsigned)sx < 64u) o = (sy << 6) + sx;
        }
        off[t] = o;
    }
    const float* Vb = V + (size_t)b * 64 * HW;
    float* Tb = T_out + (size_t)b * 64 * HW + (y << 6) + x;
    for (int ci = 0; ci < 16; ++ci) {
        int c = cq * 16 + ci;
        const float* Vc = Vb + (size_t)c * HW;
        float acc = 0.f;
#pragma unroll
        for (int t = 0; t < 9; ++t)
            acc += (off[t] >= 0) ? Vc[off[t]] : 0.f;
        Tb[(size_t)c * HW] = acc * (1.f / 9.f);
    }
}

extern "C" void kernel_launch(void* const* d_in, const int* in_sizes, int n_in,
                              void* d_out, int out_size, void* d_ws, size_t ws_size,
                              hipStream_t stream) {
    const float* V = (const float*)d_in[0];
    const float* K = (const float*)d_in[1];
    const float* Q = (const float*)d_in[2];
    float* S_out = (float*)d_out;            // 4*4096
    float* T_out = S_out + 4 * HW;           // 4*64*4096

    char* ws = (char*)d_ws;
    float* pix2q = (float*)(ws + 0);                 // 64 KB
    float* pix2k = (float*)(ws + 65536);
    float* rnq   = (float*)(ws + 131072);
    float* rnk   = (float*)(ws + 196608);
    float* part_val = (float*)(ws + 262144);         // 4*128*4096 f = 8 MB
    int*   part_arg = (int*)(ws + 8650752);          // 8 MB
    unsigned short* Aq = (unsigned short*)(ws + 17039360);   // 4*4096*192 bf16 = 6 MiB
    unsigned short* Bq = (unsigned short*)(ws + 23330816);   // 6 MiB

    prep_kernel<<<dim3(64, 4), 256, 0, stream>>>(Q, K, Aq, Bq, pix2q, pix2k);
    patchnorm_kernel<<<64, 256, 0, stream>>>(pix2q, pix2k, rnq, rnk);
    gemm_fused_kernel<<<dim3(32, 32, 4), 256, 0, stream>>>(Aq, Bq, rnk, part_val, part_arg);
    gatherS_kernel<<<dim3(64, 4), 256, 0, stream>>>(V, part_val, part_arg, rnq, S_out, T_out);
}